// Round 1
// baseline (604.572 us; speedup 1.0000x reference)
//
#include <hip/hip_runtime.h>
#include <hip/hip_bf16.h>
#include <math.h>

typedef float  f32x4_t  __attribute__((ext_vector_type(4)));
typedef short  s16x8_t  __attribute__((ext_vector_type(8)));

__device__ __forceinline__ short f2bf(float f) {
  union { float f; unsigned u; } a; a.f = f;
  unsigned r = a.u + 0x7fffu + ((a.u >> 16) & 1u);   // RNE truncate to bf16
  return (short)(r >> 16);
}
__device__ __forceinline__ float bf2f(short s) {
  union { unsigned u; float f; } a; a.u = ((unsigned)(unsigned short)s) << 16;
  return a.f;
}

__device__ __forceinline__ float wave_sum_f(float v) {
#pragma unroll
  for (int o = 32; o > 0; o >>= 1) v += __shfl_down(v, o, 64);
  return v;
}
__device__ __forceinline__ float wave_max_f(float v) {
#pragma unroll
  for (int o = 32; o > 0; o >>= 1) v = fmaxf(v, __shfl_down(v, o, 64));
  return v;
}
__device__ __forceinline__ double wave_sum_d(double v) {
#pragma unroll
  for (int o = 32; o > 0; o >>= 1) v += __shfl_down(v, o, 64);
  return v;
}
// block=256 reductions with broadcast
__device__ __forceinline__ float block_sum256(float v, float* s4) {
  v = wave_sum_f(v);
  if ((threadIdx.x & 63) == 0) s4[threadIdx.x >> 6] = v;
  __syncthreads();
  float r = s4[0] + s4[1] + s4[2] + s4[3];
  __syncthreads();
  return r;
}
__device__ __forceinline__ float block_max256(float v, float* s4) {
  v = wave_max_f(v);
  if ((threadIdx.x & 63) == 0) s4[threadIdx.x >> 6] = v;
  __syncthreads();
  float r = fmaxf(fmaxf(s4[0], s4[1]), fmaxf(s4[2], s4[3]));
  __syncthreads();
  return r;
}
__device__ __forceinline__ double block_sum256d(double v, double* s4) {
  v = wave_sum_d(v);
  if ((threadIdx.x & 63) == 0) s4[threadIdx.x >> 6] = v;
  __syncthreads();
  double r = s4[0] + s4[1] + s4[2] + s4[3];
  __syncthreads();
  return r;
}

// K0: x = l2norm(inputs); emit f32 copy + bf16 hi/lo split (for 3-MFMA f32-precision GEMM)
__global__ __launch_bounds__(256) void k0_norm(const float* __restrict__ inp,
    float* __restrict__ xf, short* __restrict__ xhi, short* __restrict__ xlo, int D) {
  __shared__ float s4[4];
  const int b = blockIdx.x, tid = threadIdx.x;
  const float4 v = *(const float4*)(inp + (size_t)b * D + tid * 4);
  const float ss = block_sum256(v.x*v.x + v.y*v.y + v.z*v.z + v.w*v.w, s4);
  const float rn = 1.0f / fmaxf(sqrtf(ss), 1e-12f);
  const float4 x = make_float4(v.x*rn, v.y*rn, v.z*rn, v.w*rn);
  *(float4*)(xf + (size_t)b * D + tid * 4) = x;
  short4 h, l;
  h.x = f2bf(x.x); l.x = f2bf(x.x - bf2f(h.x));
  h.y = f2bf(x.y); l.y = f2bf(x.y - bf2f(h.y));
  h.z = f2bf(x.z); l.z = f2bf(x.z - bf2f(h.z));
  h.w = f2bf(x.w); l.w = f2bf(x.w - bf2f(h.w));
  *(short4*)(xhi + (size_t)b * D + tid * 4) = h;
  *(short4*)(xlo + (size_t)b * D + tid * 4) = l;
}

// K1: logits[b][n] = x[b].f[n] via split-bf16 3-MFMA; fused copy features->out for rows < copy_limit.
// Block: 256 thr (4 waves), tile = 64 batch x 64 feature rows, K-step 32.
__global__ __launch_bounds__(256) void k1_gemm(
    const float* __restrict__ feat, const short* __restrict__ xhi, const short* __restrict__ xlo,
    float* __restrict__ out_feat, float* __restrict__ logits, int N, int D, int copy_limit) {
  __shared__ short lh[64 * 40];   // 40-elem row stride (80B = 5*16B): aligned + bank-spread
  __shared__ short ll[64 * 40];
  const int tid = threadIdx.x;
  const int wv = tid >> 6, lane = tid & 63;
  const int n0 = blockIdx.x * 64;
  const bool do_copy = (n0 < copy_limit);      // copy_limit is a multiple of 64 -> block-uniform
  const int r0 = tid >> 3, kg = tid & 7;       // staging: 2 float4/thread, rows r0 and r0+32
  const int r1 = r0 + 32;
  const int mrow = wv * 16 + (lane & 15);      // batch row for A-frag
  const int kgl = lane >> 4;                   // k-group 0..3
  const int lb = (lane & 15) * 40 + kgl * 8;   // B-frag LDS elem offset

  f32x4_t acc[4];
#pragma unroll
  for (int i = 0; i < 4; ++i) acc[i] = f32x4_t{0.f, 0.f, 0.f, 0.f};

  const short* xh_p = xhi + (size_t)mrow * D + kgl * 8;
  const short* xl_p = xlo + (size_t)mrow * D + kgl * 8;

  for (int kk = 0; kk < D; kk += 32) {
    const float4 v0 = *(const float4*)(feat + (size_t)(n0 + r0) * D + kk + kg * 4);
    const float4 v1 = *(const float4*)(feat + (size_t)(n0 + r1) * D + kk + kg * 4);
    if (do_copy) {  // out_feat is only 8B-aligned (OUT+18) -> float2 stores
      float* p0 = out_feat + (size_t)(n0 + r0) * D + kk + kg * 4;
      *(float2*)p0       = make_float2(v0.x, v0.y);
      *(float2*)(p0 + 2) = make_float2(v0.z, v0.w);
      float* p1 = out_feat + (size_t)(n0 + r1) * D + kk + kg * 4;
      *(float2*)p1       = make_float2(v1.x, v1.y);
      *(float2*)(p1 + 2) = make_float2(v1.z, v1.w);
    }
    __syncthreads();   // previous iteration's LDS reads complete
    {
      short4 h, l;
      h.x = f2bf(v0.x); l.x = f2bf(v0.x - bf2f(h.x));
      h.y = f2bf(v0.y); l.y = f2bf(v0.y - bf2f(h.y));
      h.z = f2bf(v0.z); l.z = f2bf(v0.z - bf2f(h.z));
      h.w = f2bf(v0.w); l.w = f2bf(v0.w - bf2f(h.w));
      *(short4*)(lh + r0 * 40 + kg * 4) = h;
      *(short4*)(ll + r0 * 40 + kg * 4) = l;
      h.x = f2bf(v1.x); l.x = f2bf(v1.x - bf2f(h.x));
      h.y = f2bf(v1.y); l.y = f2bf(v1.y - bf2f(h.y));
      h.z = f2bf(v1.z); l.z = f2bf(v1.z - bf2f(h.z));
      h.w = f2bf(v1.w); l.w = f2bf(v1.w - bf2f(h.w));
      *(short4*)(lh + r1 * 40 + kg * 4) = h;
      *(short4*)(ll + r1 * 40 + kg * 4) = l;
    }
    __syncthreads();
    const s16x8_t ah = *(const s16x8_t*)(xh_p + kk);   // L2-resident x
    const s16x8_t al = *(const s16x8_t*)(xl_p + kk);
#pragma unroll
    for (int nt = 0; nt < 4; ++nt) {
      const s16x8_t bh = *(const s16x8_t*)(lh + nt * 640 + lb);
      const s16x8_t bl = *(const s16x8_t*)(ll + nt * 640 + lb);
      acc[nt] = __builtin_amdgcn_mfma_f32_16x16x32_bf16(ah, bh, acc[nt], 0, 0, 0);
      acc[nt] = __builtin_amdgcn_mfma_f32_16x16x32_bf16(ah, bl, acc[nt], 0, 0, 0);
      acc[nt] = __builtin_amdgcn_mfma_f32_16x16x32_bf16(al, bh, acc[nt], 0, 0, 0);
    }
  }
  // C/D layout (m89-verified): col = lane&15 (n), row = (lane>>4)*4 + reg (m)
#pragma unroll
  for (int nt = 0; nt < 4; ++nt) {
    const int n = n0 + nt * 16 + (lane & 15);
#pragma unroll
    for (int r = 0; r < 4; ++r) {
      const int brow = wv * 16 + kgl * 4 + r;
      logits[(size_t)brow * N + n] = acc[nt][r];
    }
  }
}

// K2: per (row b, quarter p) streaming stats: local max M, f64 sums of exp(2(l-M)), 2l*exp(2(l-M)), exp(20(l-M))
__global__ __launch_bounds__(256) void k2_stats(const float* __restrict__ logits,
                                                double* __restrict__ partials, int N) {
  __shared__ float sf[4];
  __shared__ double sd[4];
  const int bid = blockIdx.x;
  const int b = bid >> 2, p = bid & 3;
  const int chunk = N >> 2;
  const float4* row = (const float4*)(logits + (size_t)b * N + (size_t)p * chunk);
  const int n4 = chunk >> 2;
  float m = -3.0e38f;
  for (int i = threadIdx.x; i < n4; i += 256) {
    float4 v = row[i];
    m = fmaxf(m, fmaxf(fmaxf(v.x, v.y), fmaxf(v.z, v.w)));
  }
  const float M = block_max256(m, sf);
  double s0 = 0.0, s1 = 0.0, t0 = 0.0;
  for (int i = threadIdx.x; i < n4; i += 256) {
    float4 v = row[i];
    float c, d, e2;
    c = v.x; d = c - M; e2 = __expf(2.0f*d); s0 += (double)e2; s1 += (double)(2.0f*c*e2); t0 += (double)__expf(20.0f*d);
    c = v.y; d = c - M; e2 = __expf(2.0f*d); s0 += (double)e2; s1 += (double)(2.0f*c*e2); t0 += (double)__expf(20.0f*d);
    c = v.z; d = c - M; e2 = __expf(2.0f*d); s0 += (double)e2; s1 += (double)(2.0f*c*e2); t0 += (double)__expf(20.0f*d);
    c = v.w; d = c - M; e2 = __expf(2.0f*d); s0 += (double)e2; s1 += (double)(2.0f*c*e2); t0 += (double)__expf(20.0f*d);
  }
  s0 = block_sum256d(s0, sd);
  s1 = block_sum256d(s1, sd);
  t0 = block_sum256d(t0, sd);
  if (threadIdx.x == 0) {
    double* o = partials + (size_t)bid * 4;
    o[0] = (double)M; o[1] = s0; o[2] = s1; o[3] = t0;
  }
}

// K3: merge partials (f64), score = 2M + ln s0 - s1/s0, stable rank -> top-U; loss/uloss/lam
__global__ __launch_bounds__(64) void k3_select(const double* __restrict__ partials,
    const float* __restrict__ logits, const int* __restrict__ tgt,
    float* __restrict__ OUT, int B, int N, int U) {
  __shared__ double sc[64], st0[64], lred[64], ured[64];
  const int b = threadIdx.x;
  if (b < B) {
    const double* P = partials + (size_t)b * 16;
    double M = P[0];
    for (int p = 1; p < 4; ++p) M = fmax(M, P[p * 4]);
    double s0 = 0, s1 = 0, t0 = 0;
    for (int p = 0; p < 4; ++p) {
      double mm = P[p * 4];
      double w2 = exp(2.0 * (mm - M));
      double w20 = exp(20.0 * (mm - M));
      s0 += P[p * 4 + 1] * w2; s1 += P[p * 4 + 2] * w2; t0 += P[p * 4 + 3] * w20;
    }
    sc[b]  = 2.0 * M + log(s0) - s1 / s0;   // entropy score (M cancels analytically)
    st0[b] = t0;
    const float tl = logits[(size_t)b * N + tgt[b]];
    lred[b] = 20.0 * (M - (double)tl) + log(t0);   // per-row CE loss
    ured[b] = 0.0;
  }
  __syncthreads();
  if (b < B) {
    const double s = sc[b];
    int r = 0;
    for (int j = 0; j < B; ++j) {
      const double sj = sc[j];
      r += (sj < s || (sj == s && j < b)) ? 1 : 0;   // stable ascending rank
    }
    if (r >= B - U) {
      OUT[2 + (r - (B - U))] = (float)(1.0 / st0[b]);  // lam in unc order
      ured[b] = log(st0[b]);                           // -logp(argmax) = ln t0
    }
  }
  __syncthreads();
  if (b == 0) {
    double ls = 0, us = 0;
    for (int j = 0; j < B; ++j) { ls += lred[j]; us += ured[j]; }
    OUT[0] = (float)(ls / B);
    OUT[1] = (float)(us / U);
  }
}

// K4: copy feature rows [copy_limit, N) (the region that hosted scratch) -> out
__global__ __launch_bounds__(256) void k4_tail(const float* __restrict__ feat,
    float* __restrict__ out_feat, int copy_limit, int N, int D) {
  const size_t start = (size_t)copy_limit * D;
  const size_t n2 = ((size_t)(N - copy_limit) * D) >> 1;
  const size_t stride = (size_t)gridDim.x * blockDim.x;
  for (size_t i = (size_t)blockIdx.x * blockDim.x + threadIdx.x; i < n2; i += stride) {
    const float2 v = *(const float2*)(feat + start + 2 * i);
    *(float2*)(out_feat + start + 2 * i) = v;
  }
}

// K5: sequential momentum updates; block i handles target chain starting at first occurrence i
__global__ __launch_bounds__(256) void k5_scan(const float* __restrict__ inp,
    const int* __restrict__ tgt, float* __restrict__ out_feat, int B, int D) {
  __shared__ float s4[4];
  const int i0 = blockIdx.x;
  const int y = tgt[i0];
  for (int j = 0; j < i0; ++j) if (tgt[j] == y) return;  // not first occurrence
  const int tid = threadIdx.x;
  float* rowp = out_feat + (size_t)y * D + tid * 4;
  const float2 aa = *(const float2*)rowp;
  const float2 bb = *(const float2*)(rowp + 2);
  float f0 = aa.x, f1 = aa.y, f2 = bb.x, f3 = bb.y;
  for (int occ = i0; occ < B; ++occ) {
    if (tgt[occ] != y) continue;                 // block-uniform
    const float4 xv = *(const float4*)(inp + (size_t)occ * D + tid * 4);
    const float ss = block_sum256(xv.x*xv.x + xv.y*xv.y + xv.z*xv.z + xv.w*xv.w, s4);
    const float rn = 1.0f / fmaxf(sqrtf(ss), 1e-12f);
    f0 = 0.2f * f0 + 0.8f * (xv.x * rn);
    f1 = 0.2f * f1 + 0.8f * (xv.y * rn);
    f2 = 0.2f * f2 + 0.8f * (xv.z * rn);
    f3 = 0.2f * f3 + 0.8f * (xv.w * rn);
    const float ss2 = block_sum256(f0*f0 + f1*f1 + f2*f2 + f3*f3, s4);
    const float rn2 = 1.0f / fmaxf(sqrtf(ss2), 1e-12f);
    f0 *= rn2; f1 *= rn2; f2 *= rn2; f3 *= rn2;
  }
  *(float2*)rowp       = make_float2(f0, f1);
  *(float2*)(rowp + 2) = make_float2(f2, f3);
}

extern "C" void kernel_launch(void* const* d_in, const int* in_sizes, int n_in,
                              void* d_out, int out_size, void* d_ws, size_t ws_size,
                              hipStream_t stream) {
  (void)n_in; (void)d_ws; (void)ws_size;
  const float* inp  = (const float*)d_in[0];
  const float* feat = (const float*)d_in[1];
  const int*   tgt  = (const int*)d_in[2];
  const int B = in_sizes[2];
  const int D = in_sizes[0] / B;
  const int N = in_sizes[1] / D;
  const int U = out_size - 2 - N * D;   // lam length (16)
  float* OUT = (float*)d_out;
  float* out_feat = OUT + 2 + U;        // 8B-aligned only (offset 18 floats)

  // Scratch lives in the tail rows of out_feat (no d_ws assumption); K4 overwrites it last.
  const size_t logitsE = (size_t)B * N;
  const size_t xfE     = (size_t)B * D;
  const size_t needF   = 2 + logitsE + xfE + xfE + 4096;
  int scratch_rows = (int)((needF + D - 1) / D);
  scratch_rows = ((scratch_rows + 63) / 64) * 64;
  const int copy_limit = N - scratch_rows;      // multiple of 64
  float* scratch = out_feat + (size_t)copy_limit * D + 2;  // +2 floats -> 16B aligned
  float* logits = scratch;
  float* xf = logits + logitsE;
  short* xhi = (short*)(xf + xfE);
  short* xlo = xhi + xfE;
  double* partials = (double*)(xlo + xfE);

  k0_norm  <<<B,       256, 0, stream>>>(inp, xf, xhi, xlo, D);
  k1_gemm  <<<N / 64,  256, 0, stream>>>(feat, xhi, xlo, out_feat, logits, N, D, copy_limit);
  k2_stats <<<B * 4,   256, 0, stream>>>(logits, partials, N);
  k3_select<<<1,       64,  0, stream>>>(partials, logits, tgt, OUT, B, N, U);
  k4_tail  <<<2048,    256, 0, stream>>>(feat, out_feat, copy_limit, N, D);
  k5_scan  <<<B,       256, 0, stream>>>(inp, tgt, out_feat, B, D);
}

// Round 8
// 557.970 us; speedup vs baseline: 1.0835x; 1.0835x over previous
//
#include <hip/hip_runtime.h>
#include <hip/hip_bf16.h>
#include <math.h>

typedef float  f32x4_t  __attribute__((ext_vector_type(4)));
typedef short  s16x8_t  __attribute__((ext_vector_type(8)));

__device__ __forceinline__ short f2bf(float f) {
  union { float f; unsigned u; } a; a.f = f;
  unsigned r = a.u + 0x7fffu + ((a.u >> 16) & 1u);   // RNE truncate to bf16
  return (short)(r >> 16);
}
__device__ __forceinline__ float bf2f(short s) {
  union { unsigned u; float f; } a; a.u = ((unsigned)(unsigned short)s) << 16;
  return a.f;
}

__device__ __forceinline__ float wave_sum_f(float v) {
#pragma unroll
  for (int o = 32; o > 0; o >>= 1) v += __shfl_down(v, o, 64);
  return v;
}
__device__ __forceinline__ float wave_max_f(float v) {
#pragma unroll
  for (int o = 32; o > 0; o >>= 1) v = fmaxf(v, __shfl_down(v, o, 64));
  return v;
}
__device__ __forceinline__ double wave_sum_d(double v) {
#pragma unroll
  for (int o = 32; o > 0; o >>= 1) v += __shfl_down(v, o, 64);
  return v;
}
__device__ __forceinline__ float block_sum256(float v, float* s4) {
  v = wave_sum_f(v);
  if ((threadIdx.x & 63) == 0) s4[threadIdx.x >> 6] = v;
  __syncthreads();
  float r = s4[0] + s4[1] + s4[2] + s4[3];
  __syncthreads();
  return r;
}
__device__ __forceinline__ float block_max256(float v, float* s4) {
  v = wave_max_f(v);
  if ((threadIdx.x & 63) == 0) s4[threadIdx.x >> 6] = v;
  __syncthreads();
  float r = fmaxf(fmaxf(s4[0], s4[1]), fmaxf(s4[2], s4[3]));
  __syncthreads();
  return r;
}
__device__ __forceinline__ double block_sum256d(double v, double* s4) {
  v = wave_sum_d(v);
  if ((threadIdx.x & 63) == 0) s4[threadIdx.x >> 6] = v;
  __syncthreads();
  double r = s4[0] + s4[1] + s4[2] + s4[3];
  __syncthreads();
  return r;
}

// K0: x = l2norm(inputs); emit bf16 hi/lo split (for 3-MFMA f32-precision GEMM)
__global__ __launch_bounds__(256) void k0_norm(const float* __restrict__ inp,
    short* __restrict__ xhi, short* __restrict__ xlo, int D) {
  __shared__ float s4[4];
  const int b = blockIdx.x, tid = threadIdx.x;
  const float4 v = *(const float4*)(inp + (size_t)b * D + tid * 4);
  const float ss = block_sum256(v.x*v.x + v.y*v.y + v.z*v.z + v.w*v.w, s4);
  const float rn = 1.0f / fmaxf(sqrtf(ss), 1e-12f);
  const float4 x = make_float4(v.x*rn, v.y*rn, v.z*rn, v.w*rn);
  short4 h, l;
  h.x = f2bf(x.x); l.x = f2bf(x.x - bf2f(h.x));
  h.y = f2bf(x.y); l.y = f2bf(x.y - bf2f(h.y));
  h.z = f2bf(x.z); l.z = f2bf(x.z - bf2f(h.z));
  h.w = f2bf(x.w); l.w = f2bf(x.w - bf2f(h.w));
  *(short4*)(xhi + (size_t)b * D + tid * 4) = h;
  *(short4*)(xlo + (size_t)b * D + tid * 4) = l;
}

// K1 v2: BK=64, double-buffered LDS, 1 raw barrier per K-step, reg prefetch.
// Tile: 64 batch x 64 feature rows. 4 waves. Fused feature copy.
__global__ __launch_bounds__(256, 4) void k1_gemm(
    const float* __restrict__ feat, const short* __restrict__ xhi, const short* __restrict__ xlo,
    float* __restrict__ out_feat, float* __restrict__ logits, int N, int D, int copy_limit) {
  __shared__ short lh[2][64 * 72];   // 72-short row stride: 144B (16B-aligned), conflict-free
  __shared__ short ll[2][64 * 72];
  const int tid = threadIdx.x;
  const int wv = tid >> 6, lane = tid & 63;
  const int n0 = blockIdx.x * 64;
  const bool do_copy = (n0 < copy_limit);      // block-uniform
  const int rt = tid >> 2, cg = tid & 3;       // staging: row rt, 16-float col group cg
  const int mrow = wv * 16 + (lane & 15);      // batch row for A-frag
  const int kgl = lane >> 4;                   // k-group 0..3
  const int lbo = (lane & 15) * 72 + kgl * 8;  // B-frag LDS elem offset

  f32x4_t acc[4];
#pragma unroll
  for (int i = 0; i < 4; ++i) acc[i] = f32x4_t{0.f, 0.f, 0.f, 0.f};

  const short* xh_p = xhi + (size_t)mrow * D + kgl * 8;
  const short* xl_p = xlo + (size_t)mrow * D + kgl * 8;
  const float* fsrc = feat + (size_t)(n0 + rt) * D + cg * 16;
  float*       fdst = out_feat + (size_t)(n0 + rt) * D + cg * 16;
  const int wofs = rt * 72 + cg * 16;

  float4 va[4], vb[4];
#pragma unroll
  for (int q = 0; q < 4; ++q) va[q] = *(const float4*)(fsrc + 4 * q);

  auto step = [&](float4 (&cur)[4], float4 (&nxt)[4], int buf, int kk) {
    // 1. A-frags for THIS step first (oldest in vmcnt FIFO -> MFMA wait won't drain prefetch)
    const s16x8_t ah0 = *(const s16x8_t*)(xh_p + kk);
    const s16x8_t al0 = *(const s16x8_t*)(xl_p + kk);
    const s16x8_t ah1 = *(const s16x8_t*)(xh_p + kk + 32);
    const s16x8_t al1 = *(const s16x8_t*)(xl_p + kk + 32);
    // 2. prefetch next K-tile
    const int kpf = kk + 64;
    if (kpf < D) {
#pragma unroll
      for (int q = 0; q < 4; ++q) nxt[q] = *(const float4*)(fsrc + kpf + 4 * q);
    }
    // 3. convert cur -> hi/lo, write LDS buf (b128)
    s16x8_t h0, h1, l0, l1;
    { const float4 v = cur[0];
      h0[0]=f2bf(v.x); l0[0]=f2bf(v.x-bf2f(h0[0])); h0[1]=f2bf(v.y); l0[1]=f2bf(v.y-bf2f(h0[1]));
      h0[2]=f2bf(v.z); l0[2]=f2bf(v.z-bf2f(h0[2])); h0[3]=f2bf(v.w); l0[3]=f2bf(v.w-bf2f(h0[3])); }
    { const float4 v = cur[1];
      h0[4]=f2bf(v.x); l0[4]=f2bf(v.x-bf2f(h0[4])); h0[5]=f2bf(v.y); l0[5]=f2bf(v.y-bf2f(h0[5]));
      h0[6]=f2bf(v.z); l0[6]=f2bf(v.z-bf2f(h0[6])); h0[7]=f2bf(v.w); l0[7]=f2bf(v.w-bf2f(h0[7])); }
    { const float4 v = cur[2];
      h1[0]=f2bf(v.x); l1[0]=f2bf(v.x-bf2f(h1[0])); h1[1]=f2bf(v.y); l1[1]=f2bf(v.y-bf2f(h1[1]));
      h1[2]=f2bf(v.z); l1[2]=f2bf(v.z-bf2f(h1[2])); h1[3]=f2bf(v.w); l1[3]=f2bf(v.w-bf2f(h1[3])); }
    { const float4 v = cur[3];
      h1[4]=f2bf(v.x); l1[4]=f2bf(v.x-bf2f(h1[4])); h1[5]=f2bf(v.y); l1[5]=f2bf(v.y-bf2f(h1[5]));
      h1[6]=f2bf(v.z); l1[6]=f2bf(v.z-bf2f(h1[6])); h1[7]=f2bf(v.w); l1[7]=f2bf(v.w-bf2f(h1[7])); }
    *(s16x8_t*)(&lh[buf][wofs])     = h0;
    *(s16x8_t*)(&lh[buf][wofs + 8]) = h1;
    *(s16x8_t*)(&ll[buf][wofs])     = l0;
    *(s16x8_t*)(&ll[buf][wofs + 8]) = l1;
    // 4. fused feature copy (out_feat only 8B-aligned -> float2)
    if (do_copy) {
#pragma unroll
      for (int q = 0; q < 4; ++q) {
        const float4 v = cur[q];
        *(float2*)(fdst + kk + 4 * q)     = make_float2(v.x, v.y);
        *(float2*)(fdst + kk + 4 * q + 2) = make_float2(v.z, v.w);
      }
    }
    // 5. LDS-visible barrier that does NOT drain vmcnt (keeps prefetch in flight)
    asm volatile("s_waitcnt lgkmcnt(0)" ::: "memory");
    __builtin_amdgcn_s_barrier();
    __builtin_amdgcn_sched_barrier(0);
    // 6. MFMA from buf
    const short* rbh = &lh[buf][lbo];
    const short* rbl = &ll[buf][lbo];
#pragma unroll
    for (int nt = 0; nt < 4; ++nt) {
      const s16x8_t bh0 = *(const s16x8_t*)(rbh + nt * 1152);
      const s16x8_t bl0 = *(const s16x8_t*)(rbl + nt * 1152);
      acc[nt] = __builtin_amdgcn_mfma_f32_16x16x32_bf16(ah0, bh0, acc[nt], 0, 0, 0);
      acc[nt] = __builtin_amdgcn_mfma_f32_16x16x32_bf16(ah0, bl0, acc[nt], 0, 0, 0);
      acc[nt] = __builtin_amdgcn_mfma_f32_16x16x32_bf16(al0, bh0, acc[nt], 0, 0, 0);
      const s16x8_t bh1 = *(const s16x8_t*)(rbh + nt * 1152 + 32);
      const s16x8_t bl1 = *(const s16x8_t*)(rbl + nt * 1152 + 32);
      acc[nt] = __builtin_amdgcn_mfma_f32_16x16x32_bf16(ah1, bh1, acc[nt], 0, 0, 0);
      acc[nt] = __builtin_amdgcn_mfma_f32_16x16x32_bf16(ah1, bl1, acc[nt], 0, 0, 0);
      acc[nt] = __builtin_amdgcn_mfma_f32_16x16x32_bf16(al1, bh1, acc[nt], 0, 0, 0);
    }
  };

  for (int it2 = 0; it2 < D / 128; ++it2) {
    step(va, vb, 0, it2 * 128);
    step(vb, va, 1, it2 * 128 + 64);
  }

  // C/D layout (m89-verified): col = lane&15 (n), row = (lane>>4)*4 + reg (m)
#pragma unroll
  for (int nt = 0; nt < 4; ++nt) {
    const int n = n0 + nt * 16 + (lane & 15);
#pragma unroll
    for (int r = 0; r < 4; ++r) {
      const int brow = wv * 16 + kgl * 4 + r;
      logits[(size_t)brow * N + n] = acc[nt][r];
    }
  }
}

// K2: per (row b, 1/16 chunk p) streaming stats: max M, f64 sums of exp(2(l-M)), 2l*exp(2(l-M)), exp(20(l-M))
__global__ __launch_bounds__(256) void k2_stats(const float* __restrict__ logits,
                                                double* __restrict__ partials, int N) {
  __shared__ float sf[4];
  __shared__ double sd[4];
  const int bid = blockIdx.x;
  const int b = bid >> 4, p = bid & 15;
  const int chunk = N >> 4;
  const float4* row = (const float4*)(logits + (size_t)b * N + (size_t)p * chunk);
  const int n4 = chunk >> 2;
  float m = -3.0e38f;
  for (int i = threadIdx.x; i < n4; i += 256) {
    float4 v = row[i];
    m = fmaxf(m, fmaxf(fmaxf(v.x, v.y), fmaxf(v.z, v.w)));
  }
  const float M = block_max256(m, sf);
  double s0 = 0.0, s1 = 0.0, t0 = 0.0;
  for (int i = threadIdx.x; i < n4; i += 256) {
    float4 v = row[i];
    float c, d, e2;
    c = v.x; d = c - M; e2 = __expf(2.0f*d); s0 += (double)e2; s1 += (double)(2.0f*c*e2); t0 += (double)__expf(20.0f*d);
    c = v.y; d = c - M; e2 = __expf(2.0f*d); s0 += (double)e2; s1 += (double)(2.0f*c*e2); t0 += (double)__expf(20.0f*d);
    c = v.z; d = c - M; e2 = __expf(2.0f*d); s0 += (double)e2; s1 += (double)(2.0f*c*e2); t0 += (double)__expf(20.0f*d);
    c = v.w; d = c - M; e2 = __expf(2.0f*d); s0 += (double)e2; s1 += (double)(2.0f*c*e2); t0 += (double)__expf(20.0f*d);
  }
  s0 = block_sum256d(s0, sd);
  s1 = block_sum256d(s1, sd);
  t0 = block_sum256d(t0, sd);
  if (threadIdx.x == 0) {
    double* o = partials + (size_t)bid * 4;
    o[0] = (double)M; o[1] = s0; o[2] = s1; o[3] = t0;
  }
}

// K3: merge 16 partials/row (f64), score = 2M + ln s0 - s1/s0, stable rank -> top-U; loss/uloss/lam
__global__ __launch_bounds__(64) void k3_select(const double* __restrict__ partials,
    const float* __restrict__ logits, const int* __restrict__ tgt,
    float* __restrict__ OUT, int B, int N, int U) {
  __shared__ double sc[64], st0[64], lred[64], ured[64];
  const int b = threadIdx.x;
  if (b < B) {
    const double* P = partials + (size_t)b * 64;
    double M = P[0];
    for (int p = 1; p < 16; ++p) M = fmax(M, P[p * 4]);
    double s0 = 0, s1 = 0, t0 = 0;
    for (int p = 0; p < 16; ++p) {
      double mm = P[p * 4];
      double w2 = exp(2.0 * (mm - M));
      double w20 = exp(20.0 * (mm - M));
      s0 += P[p * 4 + 1] * w2; s1 += P[p * 4 + 2] * w2; t0 += P[p * 4 + 3] * w20;
    }
    sc[b]  = 2.0 * M + log(s0) - s1 / s0;   // entropy score (M cancels analytically)
    st0[b] = t0;
    const float tl = logits[(size_t)b * N + tgt[b]];
    lred[b] = 20.0 * (M - (double)tl) + log(t0);   // per-row CE loss
    ured[b] = 0.0;
  }
  __syncthreads();
  if (b < B) {
    const double s = sc[b];
    int r = 0;
    for (int j = 0; j < B; ++j) {
      const double sj = sc[j];
      r += (sj < s || (sj == s && j < b)) ? 1 : 0;   // stable ascending rank
    }
    if (r >= B - U) {
      OUT[2 + (r - (B - U))] = (float)(1.0 / st0[b]);  // lam in unc order
      ured[b] = log(st0[b]);                           // -logp(argmax) = ln t0
    }
  }
  __syncthreads();
  if (b == 0) {
    double ls = 0, us = 0;
    for (int j = 0; j < B; ++j) { ls += lred[j]; us += ured[j]; }
    OUT[0] = (float)(ls / B);
    OUT[1] = (float)(us / U);
  }
}

// K4: copy feature rows [copy_limit, N) (the region that hosted scratch) -> out
__global__ __launch_bounds__(256) void k4_tail(const float* __restrict__ feat,
    float* __restrict__ out_feat, int copy_limit, int N, int D) {
  const size_t start = (size_t)copy_limit * D;
  const size_t n2 = ((size_t)(N - copy_limit) * D) >> 1;
  const size_t stride = (size_t)gridDim.x * blockDim.x;
  for (size_t i = (size_t)blockIdx.x * blockDim.x + threadIdx.x; i < n2; i += stride) {
    const float2 v = *(const float2*)(feat + start + 2 * i);
    *(float2*)(out_feat + start + 2 * i) = v;
  }
}

// K5: sequential momentum updates; block i handles target chain starting at first occurrence i
__global__ __launch_bounds__(256) void k5_scan(const float* __restrict__ inp,
    const int* __restrict__ tgt, float* __restrict__ out_feat, int B, int D) {
  __shared__ float s4[4];
  const int i0 = blockIdx.x;
  const int y = tgt[i0];
  for (int j = 0; j < i0; ++j) if (tgt[j] == y) return;  // not first occurrence
  const int tid = threadIdx.x;
  float* rowp = out_feat + (size_t)y * D + tid * 4;
  const float2 aa = *(const float2*)rowp;
  const float2 bb = *(const float2*)(rowp + 2);
  float f0 = aa.x, f1 = aa.y, f2 = bb.x, f3 = bb.y;
  for (int occ = i0; occ < B; ++occ) {
    if (tgt[occ] != y) continue;                 // block-uniform
    const float4 xv = *(const float4*)(inp + (size_t)occ * D + tid * 4);
    const float ss = block_sum256(xv.x*xv.x + xv.y*xv.y + xv.z*xv.z + xv.w*xv.w, s4);
    const float rn = 1.0f / fmaxf(sqrtf(ss), 1e-12f);
    f0 = 0.2f * f0 + 0.8f * (xv.x * rn);
    f1 = 0.2f * f1 + 0.8f * (xv.y * rn);
    f2 = 0.2f * f2 + 0.8f * (xv.z * rn);
    f3 = 0.2f * f3 + 0.8f * (xv.w * rn);
    const float ss2 = block_sum256(f0*f0 + f1*f1 + f2*f2 + f3*f3, s4);
    const float rn2 = 1.0f / fmaxf(sqrtf(ss2), 1e-12f);
    f0 *= rn2; f1 *= rn2; f2 *= rn2; f3 *= rn2;
  }
  *(float2*)rowp       = make_float2(f0, f1);
  *(float2*)(rowp + 2) = make_float2(f2, f3);
}

extern "C" void kernel_launch(void* const* d_in, const int* in_sizes, int n_in,
                              void* d_out, int out_size, void* d_ws, size_t ws_size,
                              hipStream_t stream) {
  (void)n_in; (void)d_ws; (void)ws_size;
  const float* inp  = (const float*)d_in[0];
  const float* feat = (const float*)d_in[1];
  const int*   tgt  = (const int*)d_in[2];
  const int B = in_sizes[2];
  const int D = in_sizes[0] / B;
  const int N = in_sizes[1] / D;
  const int U = out_size - 2 - N * D;   // lam length (16)
  float* OUT = (float*)d_out;
  float* out_feat = OUT + 2 + U;        // 8B-aligned only (offset 18 floats)

  // Scratch lives in the tail rows of out_feat (no d_ws assumption); K4 overwrites it last.
  const size_t logitsE = (size_t)B * N;
  const size_t xfE     = (size_t)B * D;
  const size_t needF   = 2 + logitsE + xfE /*xhi+xlo shorts*/ + (size_t)B * 16 * 4 * 2 /*partials*/ + 4096;
  int scratch_rows = (int)((needF + D - 1) / D);
  scratch_rows = ((scratch_rows + 63) / 64) * 64;
  const int copy_limit = N - scratch_rows;      // multiple of 64
  float* scratch = out_feat + (size_t)copy_limit * D + 2;  // +2 floats -> 16B aligned
  float* logits = scratch;
  short* xhi = (short*)(logits + logitsE);
  short* xlo = xhi + xfE;
  double* partials = (double*)(xlo + xfE);

  k0_norm  <<<B,       256, 0, stream>>>(inp, xhi, xlo, D);
  k1_gemm  <<<N / 64,  256, 0, stream>>>(feat, xhi, xlo, out_feat, logits, N, D, copy_limit);
  k2_stats <<<B * 16,  256, 0, stream>>>(logits, partials, N);
  k3_select<<<1,       64,  0, stream>>>(partials, logits, tgt, OUT, B, N, U);
  k4_tail  <<<2048,    256, 0, stream>>>(feat, out_feat, copy_limit, N, D);
  k5_scan  <<<B,       256, 0, stream>>>(inp, tgt, out_feat, B, D);
}